// Round 1
// baseline (7837.456 us; speedup 1.0000x reference)
//
#include <hip/hip_runtime.h>
#include <hip/hip_bf16.h>
#include <stdint.h>

typedef __attribute__((ext_vector_type(8))) short short8;
typedef __attribute__((ext_vector_type(4))) float f32x4;

#define DI static __device__ __forceinline__

DI unsigned short f2b(float f){
  unsigned u = __float_as_uint(f);
  u = (u + 0x7FFFu + ((u >> 16) & 1u)) >> 16;
  return (unsigned short)u;
}
DI float sigm(float x){ return 1.0f / (1.0f + __expf(-x)); }
DI float tanh_(float x){ return 1.0f - 2.0f / (__expf(2.0f*x) + 1.0f); } // safe at +/-inf

DI void unpack8(uint4 v, float* f){
  f[0] = __uint_as_float(v.x << 16); f[1] = __uint_as_float(v.x & 0xFFFF0000u);
  f[2] = __uint_as_float(v.y << 16); f[3] = __uint_as_float(v.y & 0xFFFF0000u);
  f[4] = __uint_as_float(v.z << 16); f[5] = __uint_as_float(v.z & 0xFFFF0000u);
  f[6] = __uint_as_float(v.w << 16); f[7] = __uint_as_float(v.w & 0xFFFF0000u);
}

// ---- embedding gather: Xbf[r' = t*64+b][256] = bf16(emb[input[b][t]])
__global__ void k_gather(const int* __restrict__ inp, const float* __restrict__ emb,
                         unsigned short* __restrict__ Xbf){
  int r = blockIdx.x;            // r' = t*64 + b
  int t = r >> 6, b = r & 63;
  int idx = inp[b*128 + t];
  float v = emb[(size_t)idx*256 + threadIdx.x];
  Xbf[(size_t)r*256 + threadIdx.x] = f2b(v);
}

// ---- transpose src[R][C] (rows row0..row0+R-1, leading dim ld) -> dst[C][R]; BF=1 => bf16 out
template<int BF>
__global__ void k_transpose(const float* __restrict__ src, void* __restrict__ dst,
                            int R, int C, int ld, int row0){
  __shared__ float tile[32][33];
  int tx = threadIdx.x, ty = threadIdx.y;
  int x = blockIdx.x*32 + tx;
  for (int i = 0; i < 4; i++){
    int y = blockIdx.y*32 + ty + i*8;
    if (x < C && y < R) tile[ty + i*8][tx] = src[(size_t)(row0 + y)*ld + x];
  }
  __syncthreads();
  int y2 = blockIdx.y*32 + tx;                 // R index
  for (int i = 0; i < 4; i++){
    int x2 = blockIdx.x*32 + ty + i*8;         // C index
    if (x2 < C && y2 < R){
      float v = tile[tx][ty + i*8];
      if (BF) ((unsigned short*)dst)[(size_t)x2*R + y2] = f2b(v);
      else    ((float*)dst)[(size_t)x2*R + y2] = v;
    }
  }
}

// ---- MFMA GEMM: C[m][n] = sum_k A[m][k]*Bt[n][k], A/Bt bf16 [rows][256]
// EPI 0: Z0x store (+bias b0), rows r'=(t,b), cols (g,u) -> Z0x[t][u][g][b]
// EPI 1: fused softmax partial: S[row] += sum exp(logit+bias); LT[row] = logit_tgt
template<int EPI>
__launch_bounds__(256, 2)
__global__ void k_gemm(const unsigned short* __restrict__ A, const unsigned short* __restrict__ Bt,
                       float* __restrict__ outZ, const float* __restrict__ bias,
                       const int* __restrict__ tgt, float* __restrict__ S, float* __restrict__ LT){
  __shared__ unsigned short As[128*72];
  __shared__ unsigned short Bs[128*72];
  __shared__ int tgt_s[128];
  const int m0 = blockIdx.y*128, n0 = blockIdx.x*128;
  const int tid = threadIdx.x;
  const int w = tid >> 6, l = tid & 63;
  const int quad = l >> 4, l15 = l & 15;
  const int wm = (w >> 1)*64, wn = (w & 1)*64;
  f32x4 acc[4][4] = {};
  if (EPI == 1 && tid < 128) tgt_s[tid] = tgt[m0 + tid];

  for (int k0 = 0; k0 < 256; k0 += 64){
    #pragma unroll
    for (int c = 0; c < 4; c++){
      int chunk = tid + c*256;                 // 0..1023
      int row = chunk >> 3, c8 = (chunk & 7)*8;
      uint4 av = *(const uint4*)&A [(size_t)(m0 + row)*256 + k0 + c8];
      *(uint4*)&As[row*72 + c8] = av;
      uint4 bv = *(const uint4*)&Bt[(size_t)(n0 + row)*256 + k0 + c8];
      *(uint4*)&Bs[row*72 + c8] = bv;
    }
    __syncthreads();
    #pragma unroll
    for (int ks = 0; ks < 64; ks += 32){
      short8 af[4], bfr[4];
      #pragma unroll
      for (int i = 0; i < 4; i++) af[i]  = *(short8*)&As[(wm + i*16 + l15)*72 + ks + quad*8];
      #pragma unroll
      for (int j = 0; j < 4; j++) bfr[j] = *(short8*)&Bs[(wn + j*16 + l15)*72 + ks + quad*8];
      #pragma unroll
      for (int i = 0; i < 4; i++)
        #pragma unroll
        for (int j = 0; j < 4; j++)
          acc[i][j] = __builtin_amdgcn_mfma_f32_16x16x32_bf16(af[i], bfr[j], acc[i][j], 0, 0, 0);
    }
    __syncthreads();
  }

  if (EPI == 0){
    #pragma unroll
    for (int i = 0; i < 4; i++){
      int mg = m0 + wm + i*16 + quad*4;        // rows mg..mg+3 in this reg quad
      int t = mg >> 6, b = mg & 63;
      #pragma unroll
      for (int j = 0; j < 4; j++){
        int ng = n0 + wn + j*16 + l15;
        int u = ng & 255, g = ng >> 8;
        float bb = bias[ng];
        f32x4 v = acc[i][j];
        v[0] += bb; v[1] += bb; v[2] += bb; v[3] += bb;
        *(f32x4*)&outZ[((((size_t)t*256 + u)*4) + g)*64 + b] = v;
      }
    }
  } else {
    #pragma unroll
    for (int i = 0; i < 4; i++){
      float rs[4] = {0.f,0.f,0.f,0.f};
      #pragma unroll
      for (int j = 0; j < 4; j++){
        int ng = n0 + wn + j*16 + l15;
        float bb = bias[ng];
        f32x4 v = acc[i][j];
        #pragma unroll
        for (int r = 0; r < 4; r++){
          float e = v[r] + bb;
          int mloc = wm + i*16 + quad*4 + r;
          if (tgt_s[mloc] == ng) LT[m0 + mloc] = e;
          rs[r] += __expf(e);
        }
      }
      #pragma unroll
      for (int r = 0; r < 4; r++){
        float s = rs[r];
        s += __shfl_xor(s, 1, 16);
        s += __shfl_xor(s, 2, 16);
        s += __shfl_xor(s, 4, 16);
        s += __shfl_xor(s, 8, 16);
        if (l15 == 0) atomicAdd(&S[m0 + wm + i*16 + quad*4 + r], s);
      }
    }
  }
}

// ---- persistent 2-layer LSTM. 256 WGs, WG u owns unit u of both layers.
// Phase p: layer0 @ t=p (p<128)  ||  layer1 @ t=p-1 (p>=1); 1 grid barrier per phase.
__launch_bounds__(256, 1)
__global__ void k_lstm(const float* __restrict__ Z0x, const float* __restrict__ W0hT,
                       const float* __restrict__ W1T, const float* __restrict__ b1,
                       unsigned short* __restrict__ h0g, unsigned short* __restrict__ h1g,
                       unsigned short* __restrict__ H1bf, unsigned* __restrict__ bar){
  const int u = blockIdx.x;
  const int tid = threadIdx.x;
  const int w = tid >> 6, b = tid & 63;
  __shared__ unsigned short hs[64*264];
  __shared__ float pz0 [4][4][64];
  __shared__ float pz1x[4][4][64];
  __shared__ float pz1h[4][4][64];
  float c0 = 0.f, c1 = 0.f;
  const int kw = w*64;                         // this wave's K slice

  for (int p = 0; p <= 128; p++){
    // ---- stage h0_{p-1} (bf16) into LDS
    {
      const unsigned short* src = h0g + (size_t)(p & 1)*(64*256);
      int br = tid >> 2, q = tid & 3;
      const uint4* s4 = (const uint4*)(src + br*256 + q*64);
      uint4* d4 = (uint4*)&hs[br*264 + q*64];
      #pragma unroll
      for (int i = 0; i < 8; i++) d4[i] = s4[i];
    }
    __syncthreads();
    // ---- pass A: layer0 h-part partials + layer1 x-part partials (both consume h0_{p-1})
    {
      float a0[4] = {0.f,0.f,0.f,0.f}, a1[4] = {0.f,0.f,0.f,0.f};
      const unsigned short* hrow = &hs[b*264 + kw];
      #pragma unroll
      for (int c = 0; c < 8; c++){
        float hf[8];
        unpack8(*(const uint4*)&hrow[c*8], hf);
        #pragma unroll
        for (int g = 0; g < 4; g++){
          const float* w0p = W0hT + ((size_t)(g*256+u))*256 + kw + c*8;
          const float* w1p = W1T  + ((size_t)(g*256+u))*512 + kw + c*8;
          #pragma unroll
          for (int e = 0; e < 8; e++){
            a0[g] = fmaf(hf[e], w0p[e], a0[g]);
            a1[g] = fmaf(hf[e], w1p[e], a1[g]);
          }
        }
      }
      #pragma unroll
      for (int g = 0; g < 4; g++){ pz0[w][g][b] = a0[g]; pz1x[w][g][b] = a1[g]; }
    }
    __syncthreads();
    // ---- stage h1_{p-2}
    {
      const unsigned short* src = h1g + (size_t)(p & 1)*(64*256);
      int br = tid >> 2, q = tid & 3;
      const uint4* s4 = (const uint4*)(src + br*256 + q*64);
      uint4* d4 = (uint4*)&hs[br*264 + q*64];
      #pragma unroll
      for (int i = 0; i < 8; i++) d4[i] = s4[i];
    }
    __syncthreads();
    // ---- pass B: layer1 h-part partials
    {
      float ah[4] = {0.f,0.f,0.f,0.f};
      const unsigned short* hrow = &hs[b*264 + kw];
      #pragma unroll
      for (int c = 0; c < 8; c++){
        float hf[8];
        unpack8(*(const uint4*)&hrow[c*8], hf);
        #pragma unroll
        for (int g = 0; g < 4; g++){
          const float* w1p = W1T + ((size_t)(g*256+u))*512 + 256 + kw + c*8;
          #pragma unroll
          for (int e = 0; e < 8; e++) ah[g] = fmaf(hf[e], w1p[e], ah[g]);
        }
      }
      #pragma unroll
      for (int g = 0; g < 4; g++) pz1h[w][g][b] = ah[g];
    }
    __syncthreads();
    // ---- finalize: wave0 -> layer0 cell update; wave1 -> layer1 cell update
    if (w == 0 && p < 128){
      float z[4];
      #pragma unroll
      for (int g = 0; g < 4; g++)
        z[g] = pz0[0][g][b] + pz0[1][g][b] + pz0[2][g][b] + pz0[3][g][b]
             + Z0x[((((size_t)p*256 + u)*4) + g)*64 + b];          // bias b0 already folded in
      float fi = sigm(z[0]), fj = tanh_(z[1]), ff = sigm(z[2] + 1.0f), fo = sigm(z[3]);
      c0 = c0*ff + fi*fj;
      float h0v = tanh_(c0)*fo;
      h0g[(size_t)((p+1)&1)*(64*256) + b*256 + u] = f2b(h0v);
    }
    if (w == 1 && p >= 1){
      int t = p - 1;
      float z[4];
      #pragma unroll
      for (int g = 0; g < 4; g++)
        z[g] = pz1x[0][g][b]+pz1x[1][g][b]+pz1x[2][g][b]+pz1x[3][g][b]
             + pz1h[0][g][b]+pz1h[1][g][b]+pz1h[2][g][b]+pz1h[3][g][b]
             + b1[g*256 + u];
      float fi = sigm(z[0]), fj = tanh_(z[1]), ff = sigm(z[2] + 1.0f), fo = sigm(z[3]);
      c1 = c1*ff + fi*fj;
      float h1v = tanh_(c1)*fo;
      unsigned short hb = f2b(h1v);
      h1g[(size_t)((p+1)&1)*(64*256) + b*256 + u] = hb;
      H1bf[((size_t)b*128 + t)*256 + u] = hb;                      // rows r=(b,t) for projection
    }
    // ---- grid barrier (device-scope, monotone counter)
    if (p < 128){
      __syncthreads();                       // drains vmcnt in every wave before barrier
      if (tid == 0){
        __threadfence();                     // release: h stores -> LLC
        atomicAdd(bar, 1u);
        unsigned target = (unsigned)(p + 1) * gridDim.x;
        while (__hip_atomic_load(bar, __ATOMIC_RELAXED, __HIP_MEMORY_SCOPE_AGENT) < target)
          __builtin_amdgcn_s_sleep(2);
      }
      __syncthreads();
      __threadfence();                       // acquire: invalidate stale L1/L2 before next stage
    }
  }
}

// ---- final reduce: cost = mean(log(S) - LT)
__global__ void k_reduce(const float* __restrict__ S, const float* __restrict__ LT,
                         float* __restrict__ out){
  __shared__ float red[256];
  float s = 0.f;
  for (int r = threadIdx.x; r < 8192; r += 256) s += __logf(S[r]) - LT[r];
  red[threadIdx.x] = s;
  __syncthreads();
  for (int st = 128; st > 0; st >>= 1){
    if (threadIdx.x < st) red[threadIdx.x] += red[threadIdx.x + st];
    __syncthreads();
  }
  if (threadIdx.x == 0) out[0] = red[0] / 8192.0f;
}

extern "C" void kernel_launch(void* const* d_in, const int* in_sizes, int n_in,
                              void* d_out, int out_size, void* d_ws, size_t ws_size,
                              hipStream_t stream){
  const int*   input   = (const int*)  d_in[0];
  const int*   targets = (const int*)  d_in[1];
  const float* emb     = (const float*)d_in[2];
  const float* W0      = (const float*)d_in[3];
  const float* b0      = (const float*)d_in[4];
  const float* W1      = (const float*)d_in[5];
  const float* b1      = (const float*)d_in[6];
  const float* Wsm     = (const float*)d_in[7];
  const float* sb      = (const float*)d_in[8];

  char* ws = (char*)d_ws;
  size_t off = 0;
  auto alloc = [&](size_t bytes)->char*{
    char* p = ws + off; off += (bytes + 255) & ~(size_t)255; return p;
  };
  unsigned short* Xbf  = (unsigned short*)alloc(8192ull*256*2);
  unsigned short* W0xT = (unsigned short*)alloc(1024ull*256*2);
  float*          W0hT = (float*)         alloc(1024ull*256*4);
  float*          W1T  = (float*)         alloc(1024ull*512*4);
  unsigned short* WsT  = (unsigned short*)alloc(16000ull*256*2);
  float*          Z0x  = (float*)         alloc(8192ull*1024*4);
  unsigned short* h0g  = (unsigned short*)alloc(2ull*64*256*2);
  unsigned short* h1g  = (unsigned short*)alloc(2ull*64*256*2);
  unsigned short* H1bf = (unsigned short*)alloc(8192ull*256*2);
  float*          S    = (float*)         alloc(8192ull*4);
  float*          LT   = (float*)         alloc(8192ull*4);
  unsigned*       bar  = (unsigned*)      alloc(256);

  // zero: h state buffers (h0g,h1g contiguous), S accumulators, barrier counter
  hipMemsetAsync(h0g, 0, 2ull*64*256*2 * 2, stream);
  hipMemsetAsync(S,   0, 8192ull*4, stream);
  hipMemsetAsync(bar, 0, 256, stream);

  k_gather<<<dim3(8192), dim3(256), 0, stream>>>(input, emb, Xbf);
  k_transpose<1><<<dim3(32, 8),  dim3(32,8), 0, stream>>>(W0,  (void*)W0xT, 256, 1024, 1024, 0);
  k_transpose<0><<<dim3(32, 8),  dim3(32,8), 0, stream>>>(W0,  (void*)W0hT, 256, 1024, 1024, 256);
  k_transpose<0><<<dim3(32, 16), dim3(32,8), 0, stream>>>(W1,  (void*)W1T,  512, 1024, 1024, 0);
  k_transpose<1><<<dim3(500, 8), dim3(32,8), 0, stream>>>(Wsm, (void*)WsT,  256, 16000, 16000, 0);

  // Z0x = X @ W0[:256,:] + b0   (M=8192 r'=(t,b), N=1024, K=256)
  k_gemm<0><<<dim3(8, 64), dim3(256), 0, stream>>>(Xbf, W0xT, Z0x, b0, nullptr, nullptr, nullptr);

  // persistent LSTM (cooperative: all 256 WGs co-resident)
  void* kargs[] = { (void*)&Z0x, (void*)&W0hT, (void*)&W1T, (void*)&b1,
                    (void*)&h0g, (void*)&h1g, (void*)&H1bf, (void*)&bar };
  hipLaunchCooperativeKernel((void*)k_lstm, dim3(256), dim3(256), kargs, 0, stream);

  // fused projection + log-softmax partials (M=8192 r=(b,t), N=16000, K=256)
  k_gemm<1><<<dim3(125, 64), dim3(256), 0, stream>>>(H1bf, WsT, nullptr, sb, targets, S, LT);

  k_reduce<<<dim3(1), dim3(256), 0, stream>>>(S, LT, (float*)d_out);
}

// Round 2
// 1375.629 us; speedup vs baseline: 5.6974x; 5.6974x over previous
//
#include <hip/hip_runtime.h>
#include <hip/hip_bf16.h>
#include <stdint.h>

typedef __attribute__((ext_vector_type(8))) short short8;
typedef __attribute__((ext_vector_type(4))) float f32x4;

#define DI static __device__ __forceinline__

DI unsigned short f2b(float f){
  unsigned u = __float_as_uint(f);
  u = (u + 0x7FFFu + ((u >> 16) & 1u)) >> 16;
  return (unsigned short)u;
}
DI float sigm(float x){ return 1.0f / (1.0f + __expf(-x)); }
DI float tanh_(float x){ return 1.0f - 2.0f / (__expf(2.0f*x) + 1.0f); } // safe at +/-inf

// ---- embedding gather: Xbf[r' = t*64+b][256] = bf16(emb[input[b][t]])
__global__ void k_gather(const int* __restrict__ inp, const float* __restrict__ emb,
                         unsigned short* __restrict__ Xbf){
  int r = blockIdx.x;            // r' = t*64 + b
  int t = r >> 6, b = r & 63;
  int idx = inp[b*128 + t];
  float v = emb[(size_t)idx*256 + threadIdx.x];
  Xbf[(size_t)r*256 + threadIdx.x] = f2b(v);
}

// ---- transpose src[R][C] (rows row0..row0+R-1, ld) -> dst[n(C)][R]
// BF: bf16 output. REORD: gate-interleave columns n' = (c&255)*4 + (c>>8)
template<int BF, int REORD>
__global__ void k_transpose(const float* __restrict__ src, void* __restrict__ dst,
                            int R, int C, int ld, int row0){
  __shared__ float tile[32][33];
  int tx = threadIdx.x, ty = threadIdx.y;
  int x = blockIdx.x*32 + tx;
  for (int i = 0; i < 4; i++){
    int y = blockIdx.y*32 + ty + i*8;
    if (x < C && y < R) tile[ty + i*8][tx] = src[(size_t)(row0 + y)*ld + x];
  }
  __syncthreads();
  int y2 = blockIdx.y*32 + tx;                 // R index
  for (int i = 0; i < 4; i++){
    int x2 = blockIdx.x*32 + ty + i*8;         // C index
    if (x2 < C && y2 < R){
      float v = tile[tx][ty + i*8];
      int n = REORD ? ((x2 & 255)*4 + (x2 >> 8)) : x2;
      if (BF) ((unsigned short*)dst)[(size_t)n*R + y2] = f2b(v);
      else    ((float*)dst)[(size_t)n*R + y2] = v;
    }
  }
}

// ---- MFMA GEMM: C[m][n] = sum_k A[m][k]*Bt[n][k], A/Bt bf16 [rows][256]
// EPI 0: Z0x store (+bias b0 with gate-reorder un-map), rows r'=(t,b) -> Z0x[t][n'][b]
// EPI 1: fused softmax partial: S[row] += sum exp(logit+bias); LT[row] = logit_tgt
template<int EPI>
__launch_bounds__(256, 2)
__global__ void k_gemm(const unsigned short* __restrict__ A, const unsigned short* __restrict__ Bt,
                       float* __restrict__ outZ, const float* __restrict__ bias,
                       const int* __restrict__ tgt, float* __restrict__ S, float* __restrict__ LT){
  __shared__ unsigned short As[128*72];
  __shared__ unsigned short Bs[128*72];
  __shared__ int tgt_s[128];
  const int m0 = blockIdx.y*128, n0 = blockIdx.x*128;
  const int tid = threadIdx.x;
  const int w = tid >> 6, l = tid & 63;
  const int quad = l >> 4, l15 = l & 15;
  const int wm = (w >> 1)*64, wn = (w & 1)*64;
  f32x4 acc[4][4] = {};
  if (EPI == 1 && tid < 128) tgt_s[tid] = tgt[m0 + tid];

  for (int k0 = 0; k0 < 256; k0 += 64){
    #pragma unroll
    for (int c = 0; c < 4; c++){
      int chunk = tid + c*256;                 // 0..1023
      int row = chunk >> 3, c8 = (chunk & 7)*8;
      uint4 av = *(const uint4*)&A [(size_t)(m0 + row)*256 + k0 + c8];
      *(uint4*)&As[row*72 + c8] = av;
      uint4 bv = *(const uint4*)&Bt[(size_t)(n0 + row)*256 + k0 + c8];
      *(uint4*)&Bs[row*72 + c8] = bv;
    }
    __syncthreads();
    #pragma unroll
    for (int ks = 0; ks < 64; ks += 32){
      short8 af[4], bfr[4];
      #pragma unroll
      for (int i = 0; i < 4; i++) af[i]  = *(short8*)&As[(wm + i*16 + l15)*72 + ks + quad*8];
      #pragma unroll
      for (int j = 0; j < 4; j++) bfr[j] = *(short8*)&Bs[(wn + j*16 + l15)*72 + ks + quad*8];
      #pragma unroll
      for (int i = 0; i < 4; i++)
        #pragma unroll
        for (int j = 0; j < 4; j++)
          acc[i][j] = __builtin_amdgcn_mfma_f32_16x16x32_bf16(af[i], bfr[j], acc[i][j], 0, 0, 0);
    }
    __syncthreads();
  }

  if (EPI == 0){
    #pragma unroll
    for (int i = 0; i < 4; i++){
      int mg = m0 + wm + i*16 + quad*4;        // rows mg..mg+3 in this reg quad
      int t = mg >> 6, b = mg & 63;
      #pragma unroll
      for (int j = 0; j < 4; j++){
        int ng = n0 + wn + j*16 + l15;         // n' (gate-interleaved)
        float bb = bias[(ng & 3)*256 + (ng >> 2)];
        f32x4 v = acc[i][j];
        v[0] += bb; v[1] += bb; v[2] += bb; v[3] += bb;
        *(f32x4*)&outZ[((size_t)t*1024 + ng)*64 + b] = v;
      }
    }
  } else {
    #pragma unroll
    for (int i = 0; i < 4; i++){
      float rs[4] = {0.f,0.f,0.f,0.f};
      #pragma unroll
      for (int j = 0; j < 4; j++){
        int ng = n0 + wn + j*16 + l15;
        float bb = bias[ng];
        f32x4 v = acc[i][j];
        #pragma unroll
        for (int r = 0; r < 4; r++){
          float e = v[r] + bb;
          int mloc = wm + i*16 + quad*4 + r;
          if (tgt_s[mloc] == ng) LT[m0 + mloc] = e;
          rs[r] += __expf(e);
        }
      }
      #pragma unroll
      for (int r = 0; r < 4; r++){
        float s = rs[r];
        s += __shfl_xor(s, 1, 16);
        s += __shfl_xor(s, 2, 16);
        s += __shfl_xor(s, 4, 16);
        s += __shfl_xor(s, 8, 16);
        if (l15 == 0) atomicAdd(&S[m0 + wm + i*16 + quad*4 + r], s);
      }
    }
  }
}

// ---- persistent 2-layer LSTM, 24 WGs cooperative.
// WG 0..7  : layer0, 32 units each (N=128 gate-cols, K=256)
// WG 8..23 : layer1, 16 units each (N=64  gate-cols, K=512)
// Weights live in registers (16 short8 B-fragments per wave) -> survive L2 inv.
// h stored globally in MFMA-frag-major layout: h[kb = u/8][b][u%8] bf16.
// Phase p: layer0 computes t=p (p<128), layer1 computes t=p-1 (p>=1). 1 barrier/phase.
__launch_bounds__(256, 1)
__global__ void k_lstm(const float* __restrict__ Z0x,          // [128 t][1024 n'][64 b] f32 (b0 folded)
                       const unsigned short* __restrict__ W0h, // [1024 n'][256 k] bf16
                       const unsigned short* __restrict__ W1,  // [1024 n'][512 k] bf16
                       const float* __restrict__ b1,
                       unsigned short* __restrict__ h0g,       // [2 par][32 kb][64 b][8]
                       unsigned short* __restrict__ h1g,       // [2 par][32 kb][64 b][8]
                       unsigned short* __restrict__ H1bf,      // [b*128+t][256 u]
                       unsigned* __restrict__ bar){
  __shared__ __align__(16) char smraw[65536];        // union: h-frag stage | z scratch
  unsigned short* hs = (unsigned short*)smraw;       // up to 32768 shorts (64 KB)
  float* zl = (float*)smraw;                         // up to 128*68 floats (34.8 KB)

  const int wg = blockIdx.x;
  const bool L0 = (wg < 8);
  const int tid = threadIdx.x;
  const int w = tid >> 6, l = tid & 63, quad = l >> 4, l15 = l & 15;
  const int b = tid & 63;

  short8 bw[16];               // persistent weight fragments (64 VGPRs)
  float c_st[8];
  float b1r[16];
  #pragma unroll
  for (int i = 0; i < 8; i++) c_st[i] = 0.f;

  if (L0){
    const int n0 = wg*128;
    #pragma unroll
    for (int j = 0; j < 2; j++)
      #pragma unroll
      for (int ks = 0; ks < 8; ks++)
        bw[j*8+ks] = *(const short8*)&W0h[(size_t)(n0 + w*32 + j*16 + l15)*256 + ks*32 + quad*8];
  } else {
    const int n0 = (wg-8)*64;
    #pragma unroll
    for (int ks = 0; ks < 16; ks++)
      bw[ks] = *(const short8*)&W1[(size_t)(n0 + w*16 + l15)*512 + ks*32 + quad*8];
    const int u0 = (wg-8)*16, ul0 = (tid >> 6)*4;
    #pragma unroll
    for (int ul = 0; ul < 4; ul++)
      #pragma unroll
      for (int g = 0; g < 4; g++)
        b1r[ul*4+g] = b1[g*256 + u0 + ul0 + ul];
  }

  for (int p = 0; p <= 128; p++){
    const int par = p & 1;
    if (L0){
      if (p < 128){
        // acc init from Z0x (independent of staging -> overlaps latency)
        const int n0 = wg*128;
        f32x4 acc[4][2];
        #pragma unroll
        for (int i = 0; i < 4; i++)
          #pragma unroll
          for (int j = 0; j < 2; j++){
            int cl = w*32 + j*16 + l15;
            acc[i][j] = *(const f32x4*)&Z0x[((size_t)p*1024 + n0 + cl)*64 + i*16 + quad*4];
          }
        // stage h0_{p-1} (32 KB, frag-major -> linear copy)
        const uint4* src = (const uint4*)(h0g + (size_t)par*16384);
        #pragma unroll
        for (int it = 0; it < 8; it++)
          *(uint4*)&hs[(it*256 + tid)*8] = src[it*256 + tid];
        __syncthreads();
        #pragma unroll
        for (int ks = 0; ks < 8; ks++){
          short8 a[4];
          #pragma unroll
          for (int i = 0; i < 4; i++)
            a[i] = *(const short8*)&hs[(((ks*4+quad)*64) + i*16 + l15)*8];
          #pragma unroll
          for (int i = 0; i < 4; i++)
            #pragma unroll
            for (int j = 0; j < 2; j++)
              acc[i][j] = __builtin_amdgcn_mfma_f32_16x16x32_bf16(a[i], bw[j*8+ks], acc[i][j], 0, 0, 0);
        }
        __syncthreads();                       // hs reads done; zl aliases hs
        #pragma unroll
        for (int i = 0; i < 4; i++)
          #pragma unroll
          for (int j = 0; j < 2; j++){
            int cl = w*32 + j*16 + l15;
            *(f32x4*)&zl[cl*68 + i*16 + quad*4] = acc[i][j];
          }
        __syncthreads();
        // cell update: 8 units per thread
        const int ul0 = (tid >> 6)*8;
        unsigned short hout[8];
        #pragma unroll
        for (int ui = 0; ui < 8; ui++){
          int cc = (ul0 + ui)*4;
          float zi = zl[(cc+0)*68 + b], zj = zl[(cc+1)*68 + b];
          float zf = zl[(cc+2)*68 + b], zo = zl[(cc+3)*68 + b];
          float c = c_st[ui]*sigm(zf + 1.0f) + sigm(zi)*tanh_(zj);
          c_st[ui] = c;
          hout[ui] = f2b(tanh_(c)*sigm(zo));
        }
        const int kb = wg*4 + (tid >> 6);      // (wg*32 + ul0)/8
        *(uint4*)&h0g[(size_t)(1-par)*16384 + (size_t)(kb*64 + b)*8] = *(const uint4*)hout;
      }
    } else {
      if (p >= 1){
        // stage [h0_{p-1} | h1_{p-2}] (64 KB)
        const uint4* s0 = (const uint4*)(h0g + (size_t)par*16384);
        const uint4* s1 = (const uint4*)(h1g + (size_t)par*16384);
        #pragma unroll
        for (int it = 0; it < 8; it++){
          *(uint4*)&hs[(it*256 + tid)*8]         = s0[it*256 + tid];
          *(uint4*)&hs[16384 + (it*256 + tid)*8] = s1[it*256 + tid];
        }
        __syncthreads();
        f32x4 acc[4];
        #pragma unroll
        for (int i = 0; i < 4; i++) acc[i] = (f32x4){0.f,0.f,0.f,0.f};
        #pragma unroll
        for (int ks = 0; ks < 16; ks++){       // kb = ks*4+quad runs 0..63 across hs (h0 then h1)
          short8 a[4];
          #pragma unroll
          for (int i = 0; i < 4; i++)
            a[i] = *(const short8*)&hs[(((ks*4+quad)*64) + i*16 + l15)*8];
          #pragma unroll
          for (int i = 0; i < 4; i++)
            acc[i] = __builtin_amdgcn_mfma_f32_16x16x32_bf16(a[i], bw[ks], acc[i], 0, 0, 0);
        }
        __syncthreads();                       // hs reads done; zl aliases hs
        {
          int cl = w*16 + l15;
          #pragma unroll
          for (int i = 0; i < 4; i++)
            *(f32x4*)&zl[cl*68 + i*16 + quad*4] = acc[i];
        }
        __syncthreads();
        // cell update: 4 units per thread
        const int u0 = (wg-8)*16, ul0 = (tid >> 6)*4;
        unsigned short hout[4];
        #pragma unroll
        for (int ui = 0; ui < 4; ui++){
          int cc = (ul0 + ui)*4;
          float zi = zl[(cc+0)*68 + b] + b1r[ui*4+0];
          float zj = zl[(cc+1)*68 + b] + b1r[ui*4+1];
          float zf = zl[(cc+2)*68 + b] + b1r[ui*4+2];
          float zo = zl[(cc+3)*68 + b] + b1r[ui*4+3];
          float c = c_st[ui]*sigm(zf + 1.0f) + sigm(zi)*tanh_(zj);
          c_st[ui] = c;
          hout[ui] = f2b(tanh_(c)*sigm(zo));
        }
        const int t = p - 1;
        const int u = u0 + ul0;                // multiple of 4
        *(uint2*)&h1g[(size_t)(1-par)*16384 + (size_t)((u>>3)*64 + b)*8 + (u & 7)] = *(const uint2*)hout;
        *(uint2*)&H1bf[((size_t)b*128 + t)*256 + u] = *(const uint2*)hout;
      }
    }
    // ---- grid barrier (device-scope)
    if (p < 128){
      __syncthreads();                         // drain all waves' stores
      if (tid == 0){
        __threadfence();                       // release: flush h to LLC
        atomicAdd(bar, 1u);
        unsigned target = (unsigned)(p + 1) * 24u;
        while (__hip_atomic_load(bar, __ATOMIC_RELAXED, __HIP_MEMORY_SCOPE_AGENT) < target)
          __builtin_amdgcn_s_sleep(1);
      }
      __syncthreads();
      __threadfence();                         // acquire: invalidate stale caches
    }
  }
}

// ---- final reduce: cost = mean(log(S) - LT)
__global__ void k_reduce(const float* __restrict__ S, const float* __restrict__ LT,
                         float* __restrict__ out){
  __shared__ float red[256];
  float s = 0.f;
  for (int r = threadIdx.x; r < 8192; r += 256) s += __logf(S[r]) - LT[r];
  red[threadIdx.x] = s;
  __syncthreads();
  for (int st = 128; st > 0; st >>= 1){
    if (threadIdx.x < st) red[threadIdx.x] += red[threadIdx.x + st];
    __syncthreads();
  }
  if (threadIdx.x == 0) out[0] = red[0] / 8192.0f;
}

extern "C" void kernel_launch(void* const* d_in, const int* in_sizes, int n_in,
                              void* d_out, int out_size, void* d_ws, size_t ws_size,
                              hipStream_t stream){
  const int*   input   = (const int*)  d_in[0];
  const int*   targets = (const int*)  d_in[1];
  const float* emb     = (const float*)d_in[2];
  const float* W0      = (const float*)d_in[3];
  const float* b0      = (const float*)d_in[4];
  const float* W1      = (const float*)d_in[5];
  const float* b1      = (const float*)d_in[6];
  const float* Wsm     = (const float*)d_in[7];
  const float* sb      = (const float*)d_in[8];

  char* ws = (char*)d_ws;
  size_t off = 0;
  auto alloc = [&](size_t bytes)->char*{
    char* p = ws + off; off += (bytes + 255) & ~(size_t)255; return p;
  };
  unsigned short* Xbf  = (unsigned short*)alloc(8192ull*256*2);
  unsigned short* W0xT = (unsigned short*)alloc(1024ull*256*2);
  unsigned short* W0hT = (unsigned short*)alloc(1024ull*256*2);
  unsigned short* W1T  = (unsigned short*)alloc(1024ull*512*2);
  unsigned short* WsT  = (unsigned short*)alloc(16000ull*256*2);
  float*          Z0x  = (float*)         alloc(8192ull*1024*4);
  unsigned short* h0g  = (unsigned short*)alloc(2ull*64*256*2);   // frag layout [2][32][64][8]
  unsigned short* h1g  = (unsigned short*)alloc(2ull*64*256*2);
  unsigned short* H1bf = (unsigned short*)alloc(8192ull*256*2);
  float*          S    = (float*)         alloc(8192ull*4);
  float*          LT   = (float*)         alloc(8192ull*4);
  unsigned*       bar  = (unsigned*)      alloc(256);

  hipMemsetAsync(h0g, 0, 2ull*64*256*2 * 2, stream);  // h0g+h1g contiguous
  hipMemsetAsync(S,   0, 8192ull*4, stream);
  hipMemsetAsync(bar, 0, 256, stream);

  k_gather<<<dim3(8192), dim3(256), 0, stream>>>(input, emb, Xbf);
  k_transpose<1,1><<<dim3(32, 8),  dim3(32,8), 0, stream>>>(W0,  (void*)W0xT, 256, 1024, 1024, 0);
  k_transpose<1,1><<<dim3(32, 8),  dim3(32,8), 0, stream>>>(W0,  (void*)W0hT, 256, 1024, 1024, 256);
  k_transpose<1,1><<<dim3(32, 16), dim3(32,8), 0, stream>>>(W1,  (void*)W1T,  512, 1024, 1024, 0);
  k_transpose<1,0><<<dim3(500, 8), dim3(32,8), 0, stream>>>(Wsm, (void*)WsT,  256, 16000, 16000, 0);

  // Z0x = X @ W0[:256,:] + b0   (M=8192 r'=(t,b), N=1024 n', K=256)
  k_gemm<0><<<dim3(8, 64), dim3(256), 0, stream>>>(Xbf, W0xT, Z0x, b0, nullptr, nullptr, nullptr);

  // persistent LSTM (24 WGs cooperative)
  void* kargs[] = { (void*)&Z0x, (void*)&W0hT, (void*)&W1T, (void*)&b1,
                    (void*)&h0g, (void*)&h1g, (void*)&H1bf, (void*)&bar };
  hipLaunchCooperativeKernel((void*)k_lstm, dim3(24), dim3(256), kargs, 0, stream);

  // fused projection + log-softmax partials (M=8192 r=(b,t), N=16000, K=256)
  k_gemm<1><<<dim3(125, 64), dim3(256), 0, stream>>>(H1bf, WsT, nullptr, sb, targets, S, LT);

  k_reduce<<<dim3(1), dim3(256), 0, stream>>>(S, LT, (float*)d_out);
}

// Round 3
// 1042.522 us; speedup vs baseline: 7.5178x; 1.3195x over previous
//
#include <hip/hip_runtime.h>
#include <hip/hip_bf16.h>
#include <stdint.h>

typedef __attribute__((ext_vector_type(8))) short short8;
typedef __attribute__((ext_vector_type(4))) float f32x4;
typedef unsigned long long u64;

#define DI static __device__ __forceinline__

DI unsigned short f2b(float f){
  unsigned u = __float_as_uint(f);
  u = (u + 0x7FFFu + ((u >> 16) & 1u)) >> 16;
  return (unsigned short)u;
}
DI float sigm(float x){ return 1.0f / (1.0f + __expf(-x)); }
DI float tanh_(float x){ return 1.0f - 2.0f / (__expf(2.0f*x) + 1.0f); } // safe at +/-inf

// ---- embedding gather: Xbf[r' = t*64+b][256] = bf16(emb[input[b][t]])
__global__ void k_gather(const int* __restrict__ inp, const float* __restrict__ emb,
                         unsigned short* __restrict__ Xbf){
  int r = blockIdx.x;            // r' = t*64 + b
  int t = r >> 6, b = r & 63;
  int idx = inp[b*128 + t];
  float v = emb[(size_t)idx*256 + threadIdx.x];
  Xbf[(size_t)r*256 + threadIdx.x] = f2b(v);
}

// ---- transpose src[R][C] (rows row0..row0+R-1, ld) -> dst[n(C)][R]
// BF: bf16 output. REORD: gate-interleave columns n' = (c&255)*4 + (c>>8)
template<int BF, int REORD>
__global__ void k_transpose(const float* __restrict__ src, void* __restrict__ dst,
                            int R, int C, int ld, int row0){
  __shared__ float tile[32][33];
  int tx = threadIdx.x, ty = threadIdx.y;
  int x = blockIdx.x*32 + tx;
  for (int i = 0; i < 4; i++){
    int y = blockIdx.y*32 + ty + i*8;
    if (x < C && y < R) tile[ty + i*8][tx] = src[(size_t)(row0 + y)*ld + x];
  }
  __syncthreads();
  int y2 = blockIdx.y*32 + tx;                 // R index
  for (int i = 0; i < 4; i++){
    int x2 = blockIdx.x*32 + ty + i*8;         // C index
    if (x2 < C && y2 < R){
      float v = tile[tx][ty + i*8];
      int n = REORD ? ((x2 & 255)*4 + (x2 >> 2 >> 6)) : x2;  // (x2>>8)
      if (BF) ((unsigned short*)dst)[(size_t)n*R + y2] = f2b(v);
      else    ((float*)dst)[(size_t)n*R + y2] = v;
    }
  }
}

// ---- MFMA GEMM (m97 pattern): C[m][n] = sum_k A[m][k]*Bt[n][k], A/Bt bf16 [rows][256]
// global_load_lds width-16 staging, XOR-swizzled LDS slots (unpadded 64-short rows).
// EPI 0: Z0x store (+bias b0 with gate-reorder un-map), rows r'=(t,b) -> Z0x[t][n'][b]
// EPI 1: fused softmax partial: S[row] += sum exp(logit+bias); LT[row] = logit_tgt
template<int EPI>
__launch_bounds__(256, 2)
__global__ void k_gemm(const unsigned short* __restrict__ A, const unsigned short* __restrict__ Bt,
                       float* __restrict__ outZ, const float* __restrict__ bias,
                       const int* __restrict__ tgt, float* __restrict__ S, float* __restrict__ LT){
  __shared__ unsigned short As[128*64];
  __shared__ unsigned short Bs[128*64];
  __shared__ int tgt_s[128];
  const int m0 = blockIdx.y*128, n0 = blockIdx.x*128;
  const int tid = threadIdx.x;
  const int w = tid >> 6, l = tid & 63;
  const int quad = l >> 4, l15 = l & 15;
  const int wm = (w >> 1)*64, wn = (w & 1)*64;
  const int lrow = l >> 3, ls = l & 7;         // lane -> (row-in-group, slot)
  f32x4 acc[4][4] = {};
  if (EPI == 1 && tid < 128) tgt_s[tid] = tgt[m0 + tid];

  for (int k0 = 0; k0 < 256; k0 += 64){
    #pragma unroll
    for (int it = 0; it < 4; it++){
      int row = it*32 + w*8 + lrow;
      int csrc = ls ^ (row & 7);               // XOR swizzle: slot s holds chunk s^(row&7)
      __builtin_amdgcn_global_load_lds(
        (const __attribute__((address_space(1))) unsigned*)&A[(size_t)(m0+row)*256 + k0 + csrc*8],
        (__attribute__((address_space(3))) unsigned*)&As[(it*32 + w*8)*64], 16, 0, 0);
      __builtin_amdgcn_global_load_lds(
        (const __attribute__((address_space(1))) unsigned*)&Bt[(size_t)(n0+row)*256 + k0 + csrc*8],
        (__attribute__((address_space(3))) unsigned*)&Bs[(it*32 + w*8)*64], 16, 0, 0);
    }
    __syncthreads();
    #pragma unroll
    for (int ks = 0; ks < 64; ks += 32){
      const int cki = (ks >> 3) + quad;        // k-chunk index 0..7
      short8 af[4], bfr[4];
      #pragma unroll
      for (int i = 0; i < 4; i++){
        int row = wm + i*16 + l15;
        af[i]  = *(short8*)&As[row*64 + (cki ^ (row & 7))*8];
      }
      #pragma unroll
      for (int j = 0; j < 4; j++){
        int row = wn + j*16 + l15;
        bfr[j] = *(short8*)&Bs[row*64 + (cki ^ (row & 7))*8];
      }
      #pragma unroll
      for (int i = 0; i < 4; i++)
        #pragma unroll
        for (int j = 0; j < 4; j++)
          acc[i][j] = __builtin_amdgcn_mfma_f32_16x16x32_bf16(af[i], bfr[j], acc[i][j], 0, 0, 0);
    }
    __syncthreads();
  }

  if (EPI == 0){
    #pragma unroll
    for (int i = 0; i < 4; i++){
      int mg = m0 + wm + i*16 + quad*4;        // rows mg..mg+3 in this reg quad
      int t = mg >> 6, b = mg & 63;
      #pragma unroll
      for (int j = 0; j < 4; j++){
        int ng = n0 + wn + j*16 + l15;         // n' (gate-interleaved)
        float bb = bias[(ng & 3)*256 + (ng >> 2)];
        f32x4 v = acc[i][j];
        v[0] += bb; v[1] += bb; v[2] += bb; v[3] += bb;
        *(f32x4*)&outZ[((size_t)t*1024 + ng)*64 + b] = v;
      }
    }
  } else {
    #pragma unroll
    for (int i = 0; i < 4; i++){
      float rs[4] = {0.f,0.f,0.f,0.f};
      #pragma unroll
      for (int j = 0; j < 4; j++){
        int ng = n0 + wn + j*16 + l15;
        float bb = bias[ng];
        f32x4 v = acc[i][j];
        #pragma unroll
        for (int r = 0; r < 4; r++){
          float e = v[r] + bb;
          int mloc = wm + i*16 + quad*4 + r;
          if (tgt_s[mloc] == ng) LT[m0 + mloc] = e;
          rs[r] += __expf(e);
        }
      }
      #pragma unroll
      for (int r = 0; r < 4; r++){
        float s = rs[r];
        s += __shfl_xor(s, 1, 16);
        s += __shfl_xor(s, 2, 16);
        s += __shfl_xor(s, 4, 16);
        s += __shfl_xor(s, 8, 16);
        if (l15 == 0) atomicAdd(&S[m0 + wm + i*16 + quad*4 + r], s);
      }
    }
  }
}

// ---- tagged-packet staging: load 32 u64 packets/thread from LLC (agent-scope),
// retry until every packet's tag matches, then strip tags into LDS (u32 payload each).
DI void stage32(const u64* __restrict__ src, unsigned* __restrict__ dst4, int tid, unsigned tagexp){
  u64 v[32];
  for (;;){
    bool ok = true;
    #pragma unroll
    for (int k = 0; k < 32; k++)
      v[k] = __hip_atomic_load(src + tid + k*256, __ATOMIC_RELAXED, __HIP_MEMORY_SCOPE_AGENT);
    #pragma unroll
    for (int k = 0; k < 32; k++)
      ok &= ((unsigned)(v[k] >> 32) == tagexp);
    if (ok) break;
    __builtin_amdgcn_s_sleep(1);
  }
  #pragma unroll
  for (int k = 0; k < 32; k++)
    dst4[tid + k*256] = (unsigned)v[k];
}

// ---- persistent 2-layer LSTM, 24 WGs, NO barriers / NO fences.
// h exchanged as tagged 8B packets (2 bf16 + tag=t+1) via agent-scope atomics,
// full-history ring (no reuse -> producers never wait). WGs free-run their own t-loop.
// WG 0..7: layer0 (32 units each); WG 8..23: layer1 (16 units each). Weights in regs.
__launch_bounds__(256, 1)
__global__ void k_lstm(const float* __restrict__ Z0x,          // [128 t][1024 n'][64 b] f32 (b0 folded)
                       const unsigned short* __restrict__ W0h, // [1024 n'][256 k] bf16
                       const unsigned short* __restrict__ W1,  // [1024 n'][512 k] bf16
                       const float* __restrict__ b1,
                       u64* __restrict__ h0h,                  // [128 t][8192] tagged packets
                       u64* __restrict__ h1h,                  // [128 t][8192]
                       unsigned short* __restrict__ H1bf){     // [b*128+t][256 u]
  __shared__ __align__(16) char smraw[65536];        // union: h-frag stage | z scratch
  unsigned short* hs = (unsigned short*)smraw;
  unsigned* hs4 = (unsigned*)smraw;
  float* zl = (float*)smraw;

  const int wg = blockIdx.x;
  const bool L0 = (wg < 8);
  const int tid = threadIdx.x;
  const int w = tid >> 6, l = tid & 63, quad = l >> 4, l15 = l & 15;
  const int b = tid & 63;

  short8 bw[16];               // persistent weight fragments (64 VGPRs)
  float c_st[8];
  float b1r[16];
  #pragma unroll
  for (int i = 0; i < 8; i++) c_st[i] = 0.f;

  if (L0){
    const int n0 = wg*128;
    #pragma unroll
    for (int j = 0; j < 2; j++)
      #pragma unroll
      for (int ks = 0; ks < 8; ks++)
        bw[j*8+ks] = *(const short8*)&W0h[(size_t)(n0 + w*32 + j*16 + l15)*256 + ks*32 + quad*8];
  } else {
    const int n0 = (wg-8)*64;
    #pragma unroll
    for (int ks = 0; ks < 16; ks++)
      bw[ks] = *(const short8*)&W1[(size_t)(n0 + w*16 + l15)*512 + ks*32 + quad*8];
    const int u0 = (wg-8)*16, ul0 = w*4;
    #pragma unroll
    for (int ul = 0; ul < 4; ul++)
      #pragma unroll
      for (int g = 0; g < 4; g++)
        b1r[ul*4+g] = b1[g*256 + u0 + ul0 + ul];
  }

  if (L0){
    for (int t = 0; t < 128; t++){
      const int n0 = wg*128;
      f32x4 acc[4][2];
      #pragma unroll
      for (int i = 0; i < 4; i++)
        #pragma unroll
        for (int j = 0; j < 2; j++){
          int cl = w*32 + j*16 + l15;
          acc[i][j] = *(const f32x4*)&Z0x[((size_t)t*1024 + n0 + cl)*64 + i*16 + quad*4];
        }
      if (t > 0){
        stage32(h0h + (size_t)(t-1)*8192, hs4, tid, (unsigned)t);
        __syncthreads();
        #pragma unroll
        for (int ks = 0; ks < 8; ks++){
          short8 a[4];
          #pragma unroll
          for (int i = 0; i < 4; i++)
            a[i] = *(const short8*)&hs[(((ks*4+quad)*64) + i*16 + l15)*8];
          #pragma unroll
          for (int i = 0; i < 4; i++)
            #pragma unroll
            for (int j = 0; j < 2; j++)
              acc[i][j] = __builtin_amdgcn_mfma_f32_16x16x32_bf16(a[i], bw[j*8+ks], acc[i][j], 0, 0, 0);
        }
        __syncthreads();                       // hs reads done; zl aliases hs
      }
      #pragma unroll
      for (int i = 0; i < 4; i++)
        #pragma unroll
        for (int j = 0; j < 2; j++){
          int cl = w*32 + j*16 + l15;
          *(f32x4*)&zl[cl*68 + i*16 + quad*4] = acc[i][j];
        }
      __syncthreads();
      // cell update: 8 units per thread
      const int ul0 = w*8;
      unsigned short hout[8];
      #pragma unroll
      for (int ui = 0; ui < 8; ui++){
        int cc = (ul0 + ui)*4;
        float zi = zl[(cc+0)*68 + b], zj = zl[(cc+1)*68 + b];
        float zf = zl[(cc+2)*68 + b], zo = zl[(cc+3)*68 + b];
        float c = c_st[ui]*sigm(zf + 1.0f) + sigm(zi)*tanh_(zj);
        c_st[ui] = c;
        hout[ui] = f2b(tanh_(c)*sigm(zo));
      }
      // publish tagged packets (tag = t+1)
      const size_t base = (size_t)t*8192 + ((size_t)(wg*4 + w)*64 + b)*4;
      #pragma unroll
      for (int j = 0; j < 4; j++){
        u64 val = ((u64)(unsigned)(t+1) << 32)
                | (unsigned)hout[2*j] | ((unsigned)hout[2*j+1] << 16);
        __hip_atomic_store(h0h + base + j, val, __ATOMIC_RELAXED, __HIP_MEMORY_SCOPE_AGENT);
      }
      __syncthreads();                         // zl reads done before next-iter staging
    }
  } else {
    for (int t = 0; t < 128; t++){
      // stage h0(t) (tag t+1)
      stage32(h0h + (size_t)t*8192, hs4, tid, (unsigned)(t+1));
      __syncthreads();
      f32x4 acc[4];
      #pragma unroll
      for (int i = 0; i < 4; i++) acc[i] = (f32x4){0.f,0.f,0.f,0.f};
      #pragma unroll
      for (int ks = 0; ks < 8; ks++){          // h0 half (k 0..255)
        short8 a[4];
        #pragma unroll
        for (int i = 0; i < 4; i++)
          a[i] = *(const short8*)&hs[(((ks*4+quad)*64) + i*16 + l15)*8];
        #pragma unroll
        for (int i = 0; i < 4; i++)
          acc[i] = __builtin_amdgcn_mfma_f32_16x16x32_bf16(a[i], bw[ks], acc[i], 0, 0, 0);
      }
      if (t > 0){
        // stage h1(t-1) into second LDS section (no overlap with h0 reads)
        stage32(h1h + (size_t)(t-1)*8192, hs4 + 8192, tid, (unsigned)t);
        __syncthreads();
        #pragma unroll
        for (int ks = 8; ks < 16; ks++){       // h1 half (k 256..511); kb 32..63
          short8 a[4];
          #pragma unroll
          for (int i = 0; i < 4; i++)
            a[i] = *(const short8*)&hs[(((ks*4+quad)*64) + i*16 + l15)*8];
          #pragma unroll
          for (int i = 0; i < 4; i++)
            acc[i] = __builtin_amdgcn_mfma_f32_16x16x32_bf16(a[i], bw[ks], acc[i], 0, 0, 0);
        }
      }
      __syncthreads();                         // hs reads done; zl aliases hs
      {
        int cl = w*16 + l15;
        #pragma unroll
        for (int i = 0; i < 4; i++)
          *(f32x4*)&zl[cl*68 + i*16 + quad*4] = acc[i];
      }
      __syncthreads();
      // cell update: 4 units per thread
      const int u0 = (wg-8)*16, ul0 = w*4;
      unsigned short hout[4];
      #pragma unroll
      for (int ui = 0; ui < 4; ui++){
        int cc = (ul0 + ui)*4;
        float zi = zl[(cc+0)*68 + b] + b1r[ui*4+0];
        float zj = zl[(cc+1)*68 + b] + b1r[ui*4+1];
        float zf = zl[(cc+2)*68 + b] + b1r[ui*4+2];
        float zo = zl[(cc+3)*68 + b] + b1r[ui*4+3];
        float c = c_st[ui]*sigm(zf + 1.0f) + sigm(zi)*tanh_(zj);
        c_st[ui] = c;
        hout[ui] = f2b(tanh_(c)*sigm(zo));
      }
      const int u = u0 + ul0;                  // multiple of 4
      const size_t base = (size_t)t*8192 + ((size_t)(u >> 3)*64 + b)*4 + ((u & 4) >> 1);
      #pragma unroll
      for (int j = 0; j < 2; j++){
        u64 val = ((u64)(unsigned)(t+1) << 32)
                | (unsigned)hout[2*j] | ((unsigned)hout[2*j+1] << 16);
        __hip_atomic_store(h1h + base + j, val, __ATOMIC_RELAXED, __HIP_MEMORY_SCOPE_AGENT);
      }
      *(uint2*)&H1bf[((size_t)b*128 + t)*256 + u] = *(const uint2*)hout;   // plain store
      __syncthreads();                         // zl reads done before next-iter staging
    }
  }
}

// ---- final reduce: cost = mean(log(S) - LT)
__global__ void k_reduce(const float* __restrict__ S, const float* __restrict__ LT,
                         float* __restrict__ out){
  __shared__ float red[256];
  float s = 0.f;
  for (int r = threadIdx.x; r < 8192; r += 256) s += __logf(S[r]) - LT[r];
  red[threadIdx.x] = s;
  __syncthreads();
  for (int st = 128; st > 0; st >>= 1){
    if (threadIdx.x < st) red[threadIdx.x] += red[threadIdx.x + st];
    __syncthreads();
  }
  if (threadIdx.x == 0) out[0] = red[0] / 8192.0f;
}

extern "C" void kernel_launch(void* const* d_in, const int* in_sizes, int n_in,
                              void* d_out, int out_size, void* d_ws, size_t ws_size,
                              hipStream_t stream){
  const int*   input   = (const int*)  d_in[0];
  const int*   targets = (const int*)  d_in[1];
  const float* emb     = (const float*)d_in[2];
  const float* W0      = (const float*)d_in[3];
  const float* b0      = (const float*)d_in[4];
  const float* W1      = (const float*)d_in[5];
  const float* b1      = (const float*)d_in[6];
  const float* Wsm     = (const float*)d_in[7];
  const float* sb      = (const float*)d_in[8];

  char* ws = (char*)d_ws;
  size_t off = 0;
  auto alloc = [&](size_t bytes)->char*{
    char* p = ws + off; off += (bytes + 255) & ~(size_t)255; return p;
  };
  unsigned short* Xbf  = (unsigned short*)alloc(8192ull*256*2);
  unsigned short* W0xT = (unsigned short*)alloc(1024ull*256*2);
  unsigned short* W0hT = (unsigned short*)alloc(1024ull*256*2);
  unsigned short* W1T  = (unsigned short*)alloc(1024ull*512*2);
  unsigned short* WsT  = (unsigned short*)alloc(16000ull*256*2);
  float*          Z0x  = (float*)         alloc(8192ull*1024*4);
  u64*            h0h  = (u64*)           alloc(128ull*8192*8);   // tagged history
  u64*            h1h  = (u64*)           alloc(128ull*8192*8);
  unsigned short* H1bf = (unsigned short*)alloc(8192ull*256*2);
  float*          S    = (float*)         alloc(8192ull*4);
  float*          LT   = (float*)         alloc(8192ull*4);

  hipMemsetAsync(S, 0, 8192ull*4, stream);   // h histories self-validate via tags; no memset

  k_gather<<<dim3(8192), dim3(256), 0, stream>>>(input, emb, Xbf);
  k_transpose<1,1><<<dim3(32, 8),  dim3(32,8), 0, stream>>>(W0,  (void*)W0xT, 256, 1024, 1024, 0);
  k_transpose<1,1><<<dim3(32, 8),  dim3(32,8), 0, stream>>>(W0,  (void*)W0hT, 256, 1024, 1024, 256);
  k_transpose<1,1><<<dim3(32, 16), dim3(32,8), 0, stream>>>(W1,  (void*)W1T,  512, 1024, 1024, 0);
  k_transpose<1,0><<<dim3(500, 8), dim3(32,8), 0, stream>>>(Wsm, (void*)WsT,  256, 16000, 16000, 0);

  // Z0x = X @ W0[:256,:] + b0   (M=8192 r'=(t,b), N=1024 n', K=256)
  k_gemm<0><<<dim3(8, 64), dim3(256), 0, stream>>>(Xbf, W0xT, Z0x, b0, nullptr, nullptr, nullptr);

  // persistent LSTM (24 WGs co-resident; dataflow sync, no barriers)
  void* kargs[] = { (void*)&Z0x, (void*)&W0hT, (void*)&W1T, (void*)&b1,
                    (void*)&h0h, (void*)&h1h, (void*)&H1bf };
  hipLaunchCooperativeKernel((void*)k_lstm, dim3(24), dim3(256), kargs, 0, stream);

  // fused projection + log-softmax partials (M=8192 r=(b,t), N=16000, K=256)
  k_gemm<1><<<dim3(125, 64), dim3(256), 0, stream>>>(H1bf, WsT, nullptr, sb, targets, S, LT);

  k_reduce<<<dim3(1), dim3(256), 0, stream>>>(S, LT, (float*)d_out);
}